// Round 6
// baseline (443.116 us; speedup 1.0000x reference)
//
#include <hip/hip_runtime.h>
#include <hip/hip_fp16.h>

#define HEADS 4
#define FDIM 128          // HEADS * HID
#define NEG_SLOPE 0.2f
#define SM_EPS 1e-16f
#define NBUCKET 8

typedef _Float16 f16x8 __attribute__((ext_vector_type(8)));
typedef float f32x4 __attribute__((ext_vector_type(4)));

__device__ __forceinline__ float lrelu(float v) {
  return v >= 0.f ? v : NEG_SLOPE * v;
}

// ---------- zero fill (ints) ----------
__global__ void zero_i_kernel(int* __restrict__ p, long n) {
  long i = (long)blockIdx.x * blockDim.x + threadIdx.x;
  long stride = (long)gridDim.x * blockDim.x;
  for (; i < n; i += stride) p[i] = 0;
}

// ---------- Phase A: bin edges into 8 dst-range buckets ----------
// Each block reserves a private contiguous window per bucket (one global
// atomicAdd per bucket per chunk), so every bucket cache line is written by
// exactly one block -> write traffic ~= payload, fully merged in L2.
__global__ void bin_kernel(const int* __restrict__ src,
                           const int* __restrict__ dst,
                           int* __restrict__ cursors,
                           int2* __restrict__ bpair, int bcap, int ne,
                           int rngsz) {
  __shared__ int cnt[NBUCKET], base[NBUCKET], offs[NBUCKET];
  const int CH = 4096;
  int nch = (ne + CH - 1) / CH;
  for (int c = blockIdx.x; c < nch; c += gridDim.x) {
    int beg = c * CH;
    int end = min(ne, beg + CH);
    if (threadIdx.x < NBUCKET) {
      cnt[threadIdx.x] = 0;
      offs[threadIdx.x] = 0;
    }
    __syncthreads();
    for (int i = beg + threadIdx.x; i < end; i += blockDim.x) {
      int b = dst[i] / rngsz;
      atomicAdd(&cnt[b], 1);
    }
    __syncthreads();
    if (threadIdx.x < NBUCKET)
      base[threadIdx.x] = atomicAdd(&cursors[threadIdx.x], cnt[threadIdx.x]);
    __syncthreads();
    for (int i = beg + threadIdx.x; i < end; i += blockDim.x) {
      int d = dst[i];
      int b = d / rngsz;
      int p = base[b] + atomicAdd(&offs[b], 1);
      if (p < bcap) bpair[(long)b * bcap + p] = make_int2(src[i], d);
    }
    __syncthreads();
  }
}

// ---------- Phase B: per-XCD degree histogram from local bucket ----------
// grid must be 256 (one block per CU, all co-resident) so blockIdx%8 -> XCD
// holds exactly; range-r blocks read only bucket r (~1.6 MB, L2-local).
__global__ void hist_b_kernel(const int2* __restrict__ bpair,
                              const int* __restrict__ cursors, int bcap,
                              int* __restrict__ deg) {
  int r = blockIdx.x & 7;
  int nblk = gridDim.x >> 3;
  int bi = blockIdx.x >> 3;
  int cnt = cursors[r];
  const int2* p = bpair + (long)r * bcap;
  for (int i = bi * blockDim.x + threadIdx.x; i < cnt;
       i += nblk * blockDim.x)
    atomicAdd(&deg[p[i].y], 1);
}

// ---------- 3-phase exclusive scan over deg[n] -> rowptr[n+1] ----------
#define SCAN_BLOCK 256
#define SCAN_CHUNK 1024  // 4 elems / thread

__global__ void scan1_kernel(const int* __restrict__ deg,
                             int* __restrict__ partials, int n) {
  __shared__ int sdata[SCAN_BLOCK];
  int chunk0 = blockIdx.x * SCAN_CHUNK;
  int t = threadIdx.x;
  int sum = 0;
  #pragma unroll
  for (int j = 0; j < 4; ++j) {
    int idx = chunk0 + t * 4 + j;
    if (idx < n) sum += deg[idx];
  }
  sdata[t] = sum;
  __syncthreads();
  for (int off = SCAN_BLOCK / 2; off > 0; off >>= 1) {
    if (t < off) sdata[t] += sdata[t + off];
    __syncthreads();
  }
  if (t == 0) partials[blockIdx.x] = sdata[0];
}

__global__ void scan2_kernel(int* __restrict__ partials, int nb) {
  if (threadIdx.x == 0 && blockIdx.x == 0) {
    int run = 0;
    for (int i = 0; i < nb; ++i) {
      int v = partials[i];
      partials[i] = run;
      run += v;
    }
  }
}

__global__ void scan3_kernel(const int* __restrict__ deg,
                             const int* __restrict__ partials,
                             int* __restrict__ rowptr, int n) {
  __shared__ int sdata[SCAN_BLOCK];
  int chunk0 = blockIdx.x * SCAN_CHUNK;
  int t = threadIdx.x;
  int v[4];
  int sum = 0;
  #pragma unroll
  for (int j = 0; j < 4; ++j) {
    int idx = chunk0 + t * 4 + j;
    v[j] = (idx < n) ? deg[idx] : 0;
    sum += v[j];
  }
  sdata[t] = sum;
  __syncthreads();
  for (int off = 1; off < SCAN_BLOCK; off <<= 1) {
    int val = sdata[t];
    int add = (t >= off) ? sdata[t - off] : 0;
    __syncthreads();
    sdata[t] = val + add;
    __syncthreads();
  }
  int ex = (t > 0) ? sdata[t - 1] : 0;
  int base = partials[blockIdx.x] + ex;
  #pragma unroll
  for (int j = 0; j < 4; ++j) {
    int idx = chunk0 + t * 4 + j;
    if (idx < n) {
      rowptr[idx] = base;
      base += v[j];
      if (idx == n - 1) rowptr[n] = base;
    }
  }
}

// ---------- Phase B: per-XCD CSR scatter from local bucket ----------
__global__ void scatter_b_kernel(const int2* __restrict__ bpair,
                                 const int* __restrict__ cursors, int bcap,
                                 const int* __restrict__ rowptr,
                                 int* __restrict__ fill,
                                 int* __restrict__ col) {
  int r = blockIdx.x & 7;
  int nblk = gridDim.x >> 3;
  int bi = blockIdx.x >> 3;
  int cnt = cursors[r];
  const int2* p = bpair + (long)r * bcap;
  for (int i = bi * blockDim.x + threadIdx.x; i < cnt;
       i += nblk * blockDim.x) {
    int2 e = p[i];
    int pos = rowptr[e.y] + atomicAdd(&fill[e.y], 1);
    col[pos] = e.x;
  }
}

// ---------- MFMA split-fp16 linear + fused attention coefficients ----------
__global__ __launch_bounds__(256) void mfma_linear_kernel(
    const float* __restrict__ X, const float* __restrict__ W,
    const float* __restrict__ att_s, const float* __restrict__ att_d,
    __half* __restrict__ Hh, float* __restrict__ a_s, float* __restrict__ a_d,
    int nrows, int ntiles) {
  __shared__ _Float16 WtH[128 * 128];  // 32 KB
  __shared__ _Float16 WtL[128 * 128];  // 32 KB
  int t = threadIdx.x;
  for (int idx = t; idx < 128 * 128; idx += 256) {
    int k = idx >> 7, n = idx & 127;
    float w = W[idx];
    _Float16 wh = (_Float16)w;
    _Float16 wl = (_Float16)(w - (float)wh);
    int e = n * 128 + (((k >> 3) ^ (n & 7)) << 3) + (k & 7);
    WtH[e] = wh;
    WtL[e] = wl;
  }
  __syncthreads();

  int wave = t >> 6, lane = t & 63;
  int mloc = wave >> 1;  // which m-tile of the block pair
  int nh = wave & 1;     // which 64-col half
  int l15 = lane & 15, lg = lane >> 4;

  f16x8 Bh[4][4], Bl[4][4];
  float ws[4], wd[4];
  #pragma unroll
  for (int ntl = 0; ntl < 4; ++ntl) {
    int n = nh * 64 + ntl * 16 + l15;
    ws[ntl] = att_s[n];
    wd[ntl] = att_d[n];
    #pragma unroll
    for (int kk = 0; kk < 4; ++kk) {
      int k0 = kk * 32 + lg * 8;
      int e = n * 128 + (((k0 >> 3) ^ (n & 7)) << 3);
      Bh[ntl][kk] = *(const f16x8*)&WtH[e];
      Bl[ntl][kk] = *(const f16x8*)&WtL[e];
    }
  }

  for (int mt = blockIdx.x * 2 + mloc; mt < ntiles; mt += gridDim.x * 2) {
    int row = mt * 16 + l15;
    int rclamp = row < nrows ? row : (nrows - 1);
    const float* xr = X + (long)rclamp * FDIM;
    f32x4 acc[4] = {};
    #pragma unroll
    for (int kk = 0; kk < 4; ++kk) {
      int k0 = kk * 32 + lg * 8;
      float4 v0 = *(const float4*)(xr + k0);
      float4 v1 = *(const float4*)(xr + k0 + 4);
      float xv[8] = {v0.x, v0.y, v0.z, v0.w, v1.x, v1.y, v1.z, v1.w};
      f16x8 ah, al;
      #pragma unroll
      for (int j = 0; j < 8; ++j) {
        _Float16 hh = (_Float16)xv[j];
        ah[j] = hh;
        al[j] = (_Float16)(xv[j] - (float)hh);
      }
      #pragma unroll
      for (int ntl = 0; ntl < 4; ++ntl) {
        acc[ntl] = __builtin_amdgcn_mfma_f32_16x16x32_f16(ah, Bh[ntl][kk],
                                                          acc[ntl], 0, 0, 0);
        acc[ntl] = __builtin_amdgcn_mfma_f32_16x16x32_f16(ah, Bl[ntl][kk],
                                                          acc[ntl], 0, 0, 0);
        acc[ntl] = __builtin_amdgcn_mfma_f32_16x16x32_f16(al, Bh[ntl][kk],
                                                          acc[ntl], 0, 0, 0);
      }
    }
    #pragma unroll
    for (int r = 0; r < 4; ++r) {
      int rr = mt * 16 + lg * 4 + r;
      #pragma unroll
      for (int ntl = 0; ntl < 4; ++ntl) {
        int c = nh * 64 + ntl * 16 + l15;
        if (rr < nrows) Hh[(long)rr * FDIM + c] = __float2half(acc[ntl][r]);
      }
      float vs0 = acc[0][r] * ws[0] + acc[1][r] * ws[1];
      float vs1 = acc[2][r] * ws[2] + acc[3][r] * ws[3];
      float vd0 = acc[0][r] * wd[0] + acc[1][r] * wd[1];
      float vd1 = acc[2][r] * wd[2] + acc[3][r] * wd[3];
      #pragma unroll
      for (int off = 8; off >= 1; off >>= 1) {
        vs0 += __shfl_xor(vs0, off, 64);
        vs1 += __shfl_xor(vs1, off, 64);
        vd0 += __shfl_xor(vd0, off, 64);
        vd1 += __shfl_xor(vd1, off, 64);
      }
      if (l15 == 0 && rr < nrows) {
        a_s[(long)rr * HEADS + nh * 2] = vs0;
        a_s[(long)rr * HEADS + nh * 2 + 1] = vs1;
        a_d[(long)rr * HEADS + nh * 2] = vd0;
        a_d[(long)rr * HEADS + nh * 2 + 1] = vd1;
      }
    }
  }
}

// ---------- fused GAT aggregation: one wave per destination node ----------
__global__ void gat_gather_kernel(const int* __restrict__ rowptr,
                                  const int* __restrict__ col,
                                  const __half2* __restrict__ Hh,  // [n][64]
                                  const float* __restrict__ a_s,
                                  const float* __restrict__ a_d,
                                  const float* __restrict__ bias,
                                  float* __restrict__ out,
                                  __half2* __restrict__ out_h,  // may be null
                                  int n, int do_silu) {
  int lane = threadIdx.x & 63;
  int node = blockIdx.x * (blockDim.x >> 6) + (threadIdx.x >> 6);
  if (node >= n) return;
  int beg = rowptr[node], end = rowptr[node + 1];
  int head = lane >> 4;
  float ad = a_d[(long)node * HEADS + head];
  float acc0 = 0.f, acc1 = 0.f, ssum = 0.f;
  int i = beg;
  for (; i + 4 <= end; i += 4) {
    int s0 = col[i], s1 = col[i + 1], s2 = col[i + 2], s3 = col[i + 3];
    float as0 = a_s[(long)s0 * HEADS + head];
    float as1 = a_s[(long)s1 * HEADS + head];
    float as2 = a_s[(long)s2 * HEADS + head];
    float as3 = a_s[(long)s3 * HEADS + head];
    __half2 h0 = Hh[(long)s0 * 64 + lane];
    __half2 h1 = Hh[(long)s1 * 64 + lane];
    __half2 h2 = Hh[(long)s2 * 64 + lane];
    __half2 h3 = Hh[(long)s3 * 64 + lane];
    float p0 = __expf(lrelu(as0 + ad));
    float p1 = __expf(lrelu(as1 + ad));
    float p2 = __expf(lrelu(as2 + ad));
    float p3 = __expf(lrelu(as3 + ad));
    float2 f0 = __half22float2(h0), f1 = __half22float2(h1);
    float2 f2 = __half22float2(h2), f3 = __half22float2(h3);
    acc0 += p0 * f0.x + p1 * f1.x + p2 * f2.x + p3 * f3.x;
    acc1 += p0 * f0.y + p1 * f1.y + p2 * f2.y + p3 * f3.y;
    ssum += p0 + p1 + p2 + p3;
  }
  for (; i < end; ++i) {
    int s = col[i];
    float as = a_s[(long)s * HEADS + head];
    __half2 hv = Hh[(long)s * 64 + lane];
    float p = __expf(lrelu(as + ad));
    float2 f = __half22float2(hv);
    acc0 += p * f.x;
    acc1 += p * f.y;
    ssum += p;
  }
  float inv = 1.f / (ssum + SM_EPS);
  float2 b2 = *(const float2*)(bias + 2 * lane);
  float o0 = acc0 * inv + b2.x;
  float o1 = acc1 * inv + b2.y;
  if (do_silu) {
    o0 = o0 / (1.f + __expf(-o0));
    o1 = o1 / (1.f + __expf(-o1));
  }
  *(float2*)(out + (long)node * FDIM + 2 * lane) = make_float2(o0, o1);
  if (out_h) out_h[(long)node * 64 + lane] = __floats2half2_rn(o0, o1);
}

// ---------- DistMult decoder (fp16 embeddings, f32 rel) ----------
__global__ void decoder_kernel(const __half2* __restrict__ emb_h,  // [n][64]
                               const float* __restrict__ rel_emb,
                               const int* __restrict__ hd,
                               const int* __restrict__ rl,
                               const int* __restrict__ tl,
                               float* __restrict__ out, int nq) {
  int lane = threadIdx.x & 63;
  int q = blockIdx.x * (blockDim.x >> 6) + (threadIdx.x >> 6);
  if (q >= nq) return;
  int h = hd[q], r = rl[q], t = tl[q];
  float2 eh = __half22float2(emb_h[(long)h * 64 + lane]);
  float2 et = __half22float2(emb_h[(long)t * 64 + lane]);
  float2 er = *(const float2*)(rel_emb + (long)r * FDIM + 2 * lane);
  float acc = eh.x * er.x * et.x + eh.y * er.y * et.y;
  #pragma unroll
  for (int off = 32; off > 0; off >>= 1) acc += __shfl_down(acc, off, 64);
  if (lane == 0) out[q] = 1.f / (1.f + __expf(-acc));
}

// ---------- host side ----------
extern "C" void kernel_launch(void* const* d_in, const int* in_sizes, int n_in,
                              void* d_out, int out_size, void* d_ws,
                              size_t ws_size, hipStream_t stream) {
  const float* x    = (const float*)d_in[0];
  const int*   esrc = (const int*)d_in[1];
  const int*   edst = (const int*)d_in[2];
  const int*   hidx = (const int*)d_in[3];
  const int*   rel  = (const int*)d_in[4];
  const int*   tidx = (const int*)d_in[5];
  const float* W1   = (const float*)d_in[6];
  const float* b1   = (const float*)d_in[7];
  const float* as1  = (const float*)d_in[8];
  const float* ad1  = (const float*)d_in[9];
  const float* W2   = (const float*)d_in[10];
  const float* b2   = (const float*)d_in[11];
  const float* as2  = (const float*)d_in[12];
  const float* ad2  = (const float*)d_in[13];
  const float* remb = (const float*)d_in[14];
  float* out = (float*)d_out;

  const int N_ = in_sizes[0] / FDIM;
  const int E_ = in_sizes[1];
  const int Q_ = in_sizes[3];

  // workspace layout
  float*   emb    = (float*)d_ws;                      // N*128 f32
  __half*  Hh     = (__half*)(emb + (long)N_ * FDIM);  // N*128 fp16
  __half*  emb_h  = Hh + (long)N_ * FDIM;              // N*128 fp16
  float*   a_s    = (float*)(emb_h + (long)N_ * FDIM); // N*4
  float*   a_d    = a_s + (long)N_ * HEADS;            // N*4
  int*     deg    = (int*)(a_d + (long)N_ * HEADS);    // N
  int*     fill   = deg + N_;                          // N
  int*     cursors= fill + N_;                         // 8
  int*     rowptr = cursors + NBUCKET;                 // N+1
  int*     partials = rowptr + N_ + 1;                 // <=256
  int*     colsrc = partials + 256;                    // E
  // bucket store aliases emb (only live during CSR build, before any gather)
  int2*    bpair  = (int2*)emb;
  const int bcap  = E_ / NBUCKET + 32768;              // 14.4 MB << 51 MB(emb)

  const int rngsz = (N_ + NBUCKET - 1) / NBUCKET;

  // ---- build CSR (dst-sorted src list), reused by both layers ----
  zero_i_kernel<<<512, 256, 0, stream>>>(deg, 2L * N_ + NBUCKET);
  bin_kernel<<<256, 256, 0, stream>>>(esrc, edst, cursors, bpair, bcap, E_,
                                      rngsz);
  hist_b_kernel<<<256, 256, 0, stream>>>(bpair, cursors, bcap, deg);
  int nb = (N_ + SCAN_CHUNK - 1) / SCAN_CHUNK;
  scan1_kernel<<<nb, SCAN_BLOCK, 0, stream>>>(deg, partials, N_);
  scan2_kernel<<<1, 64, 0, stream>>>(partials, nb);
  scan3_kernel<<<nb, SCAN_BLOCK, 0, stream>>>(deg, partials, rowptr, N_);
  scatter_b_kernel<<<256, 256, 0, stream>>>(bpair, cursors, bcap, rowptr,
                                            fill, colsrc);

  const int ntiles = (N_ + 15) / 16;
  for (int layer = 0; layer < 2; ++layer) {
    const float* Xin  = (layer == 0) ? x : emb;
    const float* W    = (layer == 0) ? W1 : W2;
    const float* bias = (layer == 0) ? b1 : b2;
    const float* atts = (layer == 0) ? as1 : as2;
    const float* attd = (layer == 0) ? ad1 : ad2;

    mfma_linear_kernel<<<512, 256, 0, stream>>>(Xin, W, atts, attd, Hh, a_s,
                                                a_d, N_, ntiles);
    gat_gather_kernel<<<(N_ + 3) / 4, 256, 0, stream>>>(
        rowptr, colsrc, (const __half2*)Hh, a_s, a_d, bias, emb,
        (layer == 1) ? (__half2*)emb_h : (__half2*)nullptr, N_,
        layer == 0 ? 1 : 0);
  }

  decoder_kernel<<<(Q_ + 3) / 4, 256, 0, stream>>>(
      (const __half2*)emb_h, remb, hidx, rel, tidx, out, Q_);
}

// Round 7
// 414.086 us; speedup vs baseline: 1.0701x; 1.0701x over previous
//
#include <hip/hip_runtime.h>
#include <hip/hip_fp16.h>

#define HEADS 4
#define FDIM 128          // HEADS * HID
#define NEG_SLOPE 0.2f
#define SM_EPS 1e-16f
#define NBUCKET 8

typedef _Float16 f16x8 __attribute__((ext_vector_type(8)));
typedef float f32x4 __attribute__((ext_vector_type(4)));

__device__ __forceinline__ float lrelu(float v) {
  return v >= 0.f ? v : NEG_SLOPE * v;
}

// ---------- zero fill (ints) ----------
__global__ void zero_i_kernel(int* __restrict__ p, long n) {
  long i = (long)blockIdx.x * blockDim.x + threadIdx.x;
  long stride = (long)gridDim.x * blockDim.x;
  for (; i < n; i += stride) p[i] = 0;
}

// ---------- Phase A: bin edges into 8 dst-range buckets ----------
// One block per 2048-edge chunk. Block reserves a private contiguous window
// per bucket (one global atomicAdd per bucket), so every bucket cache line
// is written by exactly one block -> writes merge in L2.
// bucket(d) = umulhi(d, 8*2^32/n) : monotone, contiguous ranges, no int div.
__global__ void bin_kernel(const int* __restrict__ src,
                           const int* __restrict__ dst,
                           int* __restrict__ cursors,
                           int2* __restrict__ bpair, int bcap, int ne,
                           int n) {
  __shared__ int cnt[NBUCKET], base[NBUCKET], offs[NBUCKET];
  unsigned mult = (unsigned)(((unsigned long long)NBUCKET << 32) / n + 1);
  int beg = blockIdx.x * 2048;
  int end = min(ne, beg + 2048);
  if (threadIdx.x < NBUCKET) {
    cnt[threadIdx.x] = 0;
    offs[threadIdx.x] = 0;
  }
  __syncthreads();
  for (int i = beg + threadIdx.x; i < end; i += blockDim.x)
    atomicAdd(&cnt[__umulhi((unsigned)dst[i], mult)], 1);
  __syncthreads();
  if (threadIdx.x < NBUCKET)
    base[threadIdx.x] = atomicAdd(&cursors[threadIdx.x], cnt[threadIdx.x]);
  __syncthreads();
  for (int i = beg + threadIdx.x; i < end; i += blockDim.x) {
    int d = dst[i];
    int b = __umulhi((unsigned)d, mult);
    int p = base[b] + atomicAdd(&offs[b], 1);
    if (p < bcap) bpair[(long)b * bcap + p] = make_int2(src[i], d);
  }
}

// ---------- Phase B: per-XCD degree histogram from local bucket ----------
// grid = 2048 (8 blocks/CU, all co-resident) so blockIdx&7 -> XCD holds;
// range-r blocks touch only deg slice r (~50 KB) + bucket r (seq read).
__global__ void hist_b_kernel(const int2* __restrict__ bpair,
                              const int* __restrict__ cursors, int bcap,
                              int* __restrict__ deg) {
  int r = blockIdx.x & 7;
  int nblk = gridDim.x >> 3;
  int bi = blockIdx.x >> 3;
  int cnt = cursors[r];
  const int2* p = bpair + (long)r * bcap;
  for (int i = bi * blockDim.x + threadIdx.x; i < cnt;
       i += nblk * blockDim.x)
    atomicAdd(&deg[p[i].y], 1);
}

// ---------- 3-phase exclusive scan over deg[n] -> rowptr[n+1] ----------
#define SCAN_BLOCK 256
#define SCAN_CHUNK 1024  // 4 elems / thread

__global__ void scan1_kernel(const int* __restrict__ deg,
                             int* __restrict__ partials, int n) {
  __shared__ int sdata[SCAN_BLOCK];
  int chunk0 = blockIdx.x * SCAN_CHUNK;
  int t = threadIdx.x;
  int sum = 0;
  #pragma unroll
  for (int j = 0; j < 4; ++j) {
    int idx = chunk0 + t * 4 + j;
    if (idx < n) sum += deg[idx];
  }
  sdata[t] = sum;
  __syncthreads();
  for (int off = SCAN_BLOCK / 2; off > 0; off >>= 1) {
    if (t < off) sdata[t] += sdata[t + off];
    __syncthreads();
  }
  if (t == 0) partials[blockIdx.x] = sdata[0];
}

// wave shfl-scan over up to 128 partials (single 64-lane wave, 2 per lane)
__global__ void scan2_kernel(int* __restrict__ partials, int nb) {
  int l = threadIdx.x;  // 64 threads
  int v0 = (l < nb) ? partials[l] : 0;
  int v1 = (l + 64 < nb) ? partials[l + 64] : 0;
  int s0 = v0;
  #pragma unroll
  for (int off = 1; off < 64; off <<= 1) {
    int t = __shfl_up(s0, off, 64);
    if (l >= off) s0 += t;
  }
  int tot0 = __shfl(s0, 63, 64);
  int s1 = v1;
  #pragma unroll
  for (int off = 1; off < 64; off <<= 1) {
    int t = __shfl_up(s1, off, 64);
    if (l >= off) s1 += t;
  }
  if (l < nb) partials[l] = s0 - v0;
  if (l + 64 < nb) partials[l + 64] = tot0 + s1 - v1;
}

__global__ void scan3_kernel(const int* __restrict__ deg,
                             const int* __restrict__ partials,
                             int* __restrict__ rowptr, int n) {
  __shared__ int sdata[SCAN_BLOCK];
  int chunk0 = blockIdx.x * SCAN_CHUNK;
  int t = threadIdx.x;
  int v[4];
  int sum = 0;
  #pragma unroll
  for (int j = 0; j < 4; ++j) {
    int idx = chunk0 + t * 4 + j;
    v[j] = (idx < n) ? deg[idx] : 0;
    sum += v[j];
  }
  sdata[t] = sum;
  __syncthreads();
  for (int off = 1; off < SCAN_BLOCK; off <<= 1) {
    int val = sdata[t];
    int add = (t >= off) ? sdata[t - off] : 0;
    __syncthreads();
    sdata[t] = val + add;
    __syncthreads();
  }
  int ex = (t > 0) ? sdata[t - 1] : 0;
  int base = partials[blockIdx.x] + ex;
  #pragma unroll
  for (int j = 0; j < 4; ++j) {
    int idx = chunk0 + t * 4 + j;
    if (idx < n) {
      rowptr[idx] = base;
      base += v[j];
      if (idx == n - 1) rowptr[n] = base;
    }
  }
}

// ---------- Phase B: per-XCD CSR scatter from local bucket ----------
__global__ void scatter_b_kernel(const int2* __restrict__ bpair,
                                 const int* __restrict__ cursors, int bcap,
                                 const int* __restrict__ rowptr,
                                 int* __restrict__ fill,
                                 int* __restrict__ col) {
  int r = blockIdx.x & 7;
  int nblk = gridDim.x >> 3;
  int bi = blockIdx.x >> 3;
  int cnt = cursors[r];
  const int2* p = bpair + (long)r * bcap;
  for (int i = bi * blockDim.x + threadIdx.x; i < cnt;
       i += nblk * blockDim.x) {
    int2 e = p[i];
    int pos = rowptr[e.y] + atomicAdd(&fill[e.y], 1);
    col[pos] = e.x;
  }
}

// ---------- MFMA split-fp16 linear + fused attention coefficients ----------
// Hh = f16(X @ W). f32 input: xh*wh + xh*wl + xl*wh. fp16 input (layer 2,
// exact in fp16 so xl==0): x*wh + x*wl.
template <bool IN16>
__global__ __launch_bounds__(256) void mfma_linear_kernel(
    const float* __restrict__ Xf, const __half* __restrict__ X16,
    const float* __restrict__ W, const float* __restrict__ att_s,
    const float* __restrict__ att_d, __half* __restrict__ Hh,
    float* __restrict__ a_s, float* __restrict__ a_d, int nrows, int ntiles) {
  __shared__ _Float16 WtH[128 * 128];  // 32 KB
  __shared__ _Float16 WtL[128 * 128];  // 32 KB
  int t = threadIdx.x;
  // stage W transposed + fp16-split + swizzled; float4 vectorized reads
  for (int i4 = t; i4 < 4096; i4 += 256) {
    float4 w4 = ((const float4*)W)[i4];
    int flat = i4 * 4;
    int k = flat >> 7, n0 = flat & 127;
    float wv[4] = {w4.x, w4.y, w4.z, w4.w};
    #pragma unroll
    for (int j = 0; j < 4; ++j) {
      int n = n0 + j;
      _Float16 wh = (_Float16)wv[j];
      _Float16 wl = (_Float16)(wv[j] - (float)wh);
      int e = n * 128 + (((k >> 3) ^ (n & 7)) << 3) + (k & 7);
      WtH[e] = wh;
      WtL[e] = wl;
    }
  }
  __syncthreads();

  int wave = t >> 6, lane = t & 63;
  int mloc = wave >> 1;  // which m-tile of the block pair
  int nh = wave & 1;     // which 64-col half
  int l15 = lane & 15, lg = lane >> 4;

  f16x8 Bh[4][4], Bl[4][4];
  float ws[4], wd[4];
  #pragma unroll
  for (int ntl = 0; ntl < 4; ++ntl) {
    int n = nh * 64 + ntl * 16 + l15;
    ws[ntl] = att_s[n];
    wd[ntl] = att_d[n];
    #pragma unroll
    for (int kk = 0; kk < 4; ++kk) {
      int k0 = kk * 32 + lg * 8;
      int e = n * 128 + (((k0 >> 3) ^ (n & 7)) << 3);
      Bh[ntl][kk] = *(const f16x8*)&WtH[e];
      Bl[ntl][kk] = *(const f16x8*)&WtL[e];
    }
  }

  for (int mt = blockIdx.x * 2 + mloc; mt < ntiles; mt += gridDim.x * 2) {
    int row = mt * 16 + l15;
    int rclamp = row < nrows ? row : (nrows - 1);
    f32x4 acc[4] = {};
    #pragma unroll
    for (int kk = 0; kk < 4; ++kk) {
      int k0 = kk * 32 + lg * 8;
      f16x8 ah, al;
      if constexpr (IN16) {
        ah = *(const f16x8*)(X16 + (long)rclamp * FDIM + k0);
      } else {
        const float* xr = Xf + (long)rclamp * FDIM;
        float4 v0 = *(const float4*)(xr + k0);
        float4 v1 = *(const float4*)(xr + k0 + 4);
        float xv[8] = {v0.x, v0.y, v0.z, v0.w, v1.x, v1.y, v1.z, v1.w};
        #pragma unroll
        for (int j = 0; j < 8; ++j) {
          _Float16 hh = (_Float16)xv[j];
          ah[j] = hh;
          al[j] = (_Float16)(xv[j] - (float)hh);
        }
      }
      #pragma unroll
      for (int ntl = 0; ntl < 4; ++ntl) {
        acc[ntl] = __builtin_amdgcn_mfma_f32_16x16x32_f16(ah, Bh[ntl][kk],
                                                          acc[ntl], 0, 0, 0);
        acc[ntl] = __builtin_amdgcn_mfma_f32_16x16x32_f16(ah, Bl[ntl][kk],
                                                          acc[ntl], 0, 0, 0);
        if constexpr (!IN16)
          acc[ntl] = __builtin_amdgcn_mfma_f32_16x16x32_f16(al, Bh[ntl][kk],
                                                            acc[ntl], 0, 0, 0);
      }
    }
    #pragma unroll
    for (int r = 0; r < 4; ++r) {
      int rr = mt * 16 + lg * 4 + r;
      #pragma unroll
      for (int ntl = 0; ntl < 4; ++ntl) {
        int c = nh * 64 + ntl * 16 + l15;
        if (rr < nrows) Hh[(long)rr * FDIM + c] = __float2half(acc[ntl][r]);
      }
      float vs0 = acc[0][r] * ws[0] + acc[1][r] * ws[1];
      float vs1 = acc[2][r] * ws[2] + acc[3][r] * ws[3];
      float vd0 = acc[0][r] * wd[0] + acc[1][r] * wd[1];
      float vd1 = acc[2][r] * wd[2] + acc[3][r] * wd[3];
      #pragma unroll
      for (int off = 8; off >= 1; off >>= 1) {
        vs0 += __shfl_xor(vs0, off, 64);
        vs1 += __shfl_xor(vs1, off, 64);
        vd0 += __shfl_xor(vd0, off, 64);
        vd1 += __shfl_xor(vd1, off, 64);
      }
      if (l15 == 0 && rr < nrows) {
        a_s[(long)rr * HEADS + nh * 2] = vs0;
        a_s[(long)rr * HEADS + nh * 2 + 1] = vs1;
        a_d[(long)rr * HEADS + nh * 2] = vd0;
        a_d[(long)rr * HEADS + nh * 2 + 1] = vd1;
      }
    }
  }
}

// ---------- fused GAT aggregation: one wave per destination node ----------
// Lane owns channels {2l, 2l+1} (one head), accumulates in f32, writes fp16.
// 8-wide load batches: 8 col + 8 a_s + 8 Hh requests in flight per wave.
__global__ void gat_gather_kernel(const int* __restrict__ rowptr,
                                  const int* __restrict__ col,
                                  const __half2* __restrict__ Hh,  // [n][64]
                                  const float* __restrict__ a_s,
                                  const float* __restrict__ a_d,
                                  const float* __restrict__ bias,
                                  __half2* __restrict__ out_h,  // [n][64]
                                  int n, int do_silu) {
  int lane = threadIdx.x & 63;
  int node = blockIdx.x * (blockDim.x >> 6) + (threadIdx.x >> 6);
  if (node >= n) return;
  int beg = rowptr[node], end = rowptr[node + 1];
  int head = lane >> 4;
  float ad = a_d[node * HEADS + head];
  float acc0 = 0.f, acc1 = 0.f, ssum = 0.f;
  int i = beg;
  for (; i + 8 <= end; i += 8) {
    int sv[8];
    float asv[8];
    __half2 hv[8];
    #pragma unroll
    for (int j = 0; j < 8; ++j) sv[j] = col[i + j];
    #pragma unroll
    for (int j = 0; j < 8; ++j) asv[j] = a_s[sv[j] * HEADS + head];
    #pragma unroll
    for (int j = 0; j < 8; ++j) hv[j] = Hh[sv[j] * 64 + lane];
    #pragma unroll
    for (int j = 0; j < 8; ++j) {
      float p = __expf(lrelu(asv[j] + ad));
      float2 f = __half22float2(hv[j]);
      acc0 += p * f.x;
      acc1 += p * f.y;
      ssum += p;
    }
  }
  for (; i + 4 <= end; i += 4) {
    int sv[4];
    float asv[4];
    __half2 hv[4];
    #pragma unroll
    for (int j = 0; j < 4; ++j) sv[j] = col[i + j];
    #pragma unroll
    for (int j = 0; j < 4; ++j) asv[j] = a_s[sv[j] * HEADS + head];
    #pragma unroll
    for (int j = 0; j < 4; ++j) hv[j] = Hh[sv[j] * 64 + lane];
    #pragma unroll
    for (int j = 0; j < 4; ++j) {
      float p = __expf(lrelu(asv[j] + ad));
      float2 f = __half22float2(hv[j]);
      acc0 += p * f.x;
      acc1 += p * f.y;
      ssum += p;
    }
  }
  for (; i < end; ++i) {
    int s = col[i];
    float as = a_s[s * HEADS + head];
    __half2 hv = Hh[s * 64 + lane];
    float p = __expf(lrelu(as + ad));
    float2 f = __half22float2(hv);
    acc0 += p * f.x;
    acc1 += p * f.y;
    ssum += p;
  }
  float inv = 1.f / (ssum + SM_EPS);
  float2 b2 = *(const float2*)(bias + 2 * lane);
  float o0 = acc0 * inv + b2.x;
  float o1 = acc1 * inv + b2.y;
  if (do_silu) {
    o0 = o0 / (1.f + __expf(-o0));
    o1 = o1 / (1.f + __expf(-o1));
  }
  out_h[node * 64 + lane] = __floats2half2_rn(o0, o1);
}

// ---------- DistMult decoder (fp16 embeddings, f32 rel) ----------
__global__ void decoder_kernel(const __half2* __restrict__ emb_h,  // [n][64]
                               const float* __restrict__ rel_emb,
                               const int* __restrict__ hd,
                               const int* __restrict__ rl,
                               const int* __restrict__ tl,
                               float* __restrict__ out, int nq) {
  int lane = threadIdx.x & 63;
  int q = blockIdx.x * (blockDim.x >> 6) + (threadIdx.x >> 6);
  if (q >= nq) return;
  int h = hd[q], r = rl[q], t = tl[q];
  float2 eh = __half22float2(emb_h[(long)h * 64 + lane]);
  float2 et = __half22float2(emb_h[(long)t * 64 + lane]);
  float2 er = *(const float2*)(rel_emb + (long)r * FDIM + 2 * lane);
  float acc = eh.x * er.x * et.x + eh.y * er.y * et.y;
  #pragma unroll
  for (int off = 32; off > 0; off >>= 1) acc += __shfl_down(acc, off, 64);
  if (lane == 0) out[q] = 1.f / (1.f + __expf(-acc));
}

// ---------- host side ----------
extern "C" void kernel_launch(void* const* d_in, const int* in_sizes, int n_in,
                              void* d_out, int out_size, void* d_ws,
                              size_t ws_size, hipStream_t stream) {
  const float* x    = (const float*)d_in[0];
  const int*   esrc = (const int*)d_in[1];
  const int*   edst = (const int*)d_in[2];
  const int*   hidx = (const int*)d_in[3];
  const int*   rel  = (const int*)d_in[4];
  const int*   tidx = (const int*)d_in[5];
  const float* W1   = (const float*)d_in[6];
  const float* b1   = (const float*)d_in[7];
  const float* as1  = (const float*)d_in[8];
  const float* ad1  = (const float*)d_in[9];
  const float* W2   = (const float*)d_in[10];
  const float* b2   = (const float*)d_in[11];
  const float* as2  = (const float*)d_in[12];
  const float* ad2  = (const float*)d_in[13];
  const float* remb = (const float*)d_in[14];
  float* out = (float*)d_out;

  const int N_ = in_sizes[0] / FDIM;
  const int E_ = in_sizes[1];
  const int Q_ = in_sizes[3];

  // workspace layout (all fp16 intermediates)
  __half* Hh     = (__half*)d_ws;                      // N*128 (gemm out)
  __half* h1_h   = Hh + (long)N_ * FDIM;               // N*128 (layer1 out)
  __half* emb_h  = h1_h + (long)N_ * FDIM;             // N*128 (layer2 out)
  float*  a_s    = (float*)(emb_h + (long)N_ * FDIM);  // N*4
  float*  a_d    = a_s + (long)N_ * HEADS;             // N*4
  int*    deg    = (int*)(a_d + (long)N_ * HEADS);     // N
  int*    fill   = deg + N_;                           // N
  int*    cursors= fill + N_;                          // 8
  int*    rowptr = cursors + NBUCKET;                  // N+1
  int*    partials = rowptr + N_ + 1;                  // <=256
  int*    colsrc = partials + 256;                     // E
  // bucket store aliases h1_h (CSR build completes before layer-1 gather)
  int2*   bpair  = (int2*)h1_h;
  const int bcap = E_ / NBUCKET + 32768;

  // ---- build CSR (dst-sorted src list), reused by both layers ----
  zero_i_kernel<<<512, 256, 0, stream>>>(deg, 2L * N_ + NBUCKET);
  bin_kernel<<<(E_ + 2047) / 2048, 256, 0, stream>>>(esrc, edst, cursors,
                                                     bpair, bcap, E_, N_);
  hist_b_kernel<<<2048, 256, 0, stream>>>(bpair, cursors, bcap, deg);
  int nb = (N_ + SCAN_CHUNK - 1) / SCAN_CHUNK;
  scan1_kernel<<<nb, SCAN_BLOCK, 0, stream>>>(deg, partials, N_);
  scan2_kernel<<<1, 64, 0, stream>>>(partials, nb);
  scan3_kernel<<<nb, SCAN_BLOCK, 0, stream>>>(deg, partials, rowptr, N_);
  scatter_b_kernel<<<2048, 256, 0, stream>>>(bpair, cursors, bcap, rowptr,
                                             fill, colsrc);

  const int ntiles = (N_ + 15) / 16;
  // layer 1: f32 input x -> Hh; gather -> h1_h (SiLU)
  mfma_linear_kernel<false><<<256, 256, 0, stream>>>(
      x, (const __half*)nullptr, W1, as1, ad1, Hh, a_s, a_d, N_, ntiles);
  gat_gather_kernel<<<(N_ + 3) / 4, 256, 0, stream>>>(
      rowptr, colsrc, (const __half2*)Hh, a_s, a_d, b1, (__half2*)h1_h, N_,
      1);
  // layer 2: fp16 input h1_h -> Hh; gather -> emb_h
  mfma_linear_kernel<true><<<256, 256, 0, stream>>>(
      (const float*)nullptr, h1_h, W2, as2, ad2, Hh, a_s, a_d, N_, ntiles);
  gat_gather_kernel<<<(N_ + 3) / 4, 256, 0, stream>>>(
      rowptr, colsrc, (const __half2*)Hh, a_s, a_d, b2, (__half2*)emb_h, N_,
      0);

  decoder_kernel<<<(Q_ + 3) / 4, 256, 0, stream>>>(
      (const __half2*)emb_h, remb, hidx, rel, tidx, out, Q_);
}